// Round 11
// baseline (286.847 us; speedup 1.0000x reference)
//
#include <hip/hip_runtime.h>
#include <math.h>

// ---------------------------------------------------------------------------
// QCNN forward — DIAGNOSTIC ROUND (x32 amplification of sim chain + reduce).
//
// Structure identical to R10 (passed, 19.67 us). Two changes, correctness-
// preserving:
//   K1: gate chain repeated 32x; each iteration re-seeded with an opaque zero
//       (asm volatile v_mov) and kept live with an asm sink -> compiler cannot
//       hoist/collapse. Final iteration's z is written (identical values).
//   K2: Hermitian reduce repeated 32x with opaque-zero accumulator seeds;
//       stab rewritten with identical values each rep.
// Purpose: force qcnn_sim / qcnn_eval into rocprof top-5 (above the 39 us
// harness fills) to directly measure T_sim and T_reduce and discriminate
// H_chain (~15 us gate chain) vs H_floor (~19.6 us harness floor).
//
// Qubit->mask: q0=8 q1=1 q2=4 q3=64 q4=16 q5=128 q6=32 q7=2
// Z-signs for reduce: q3 -> k bit6 (= m&1); q7 -> k bit1 (= lane bit1).
// ---------------------------------------------------------------------------

#define QF 0.70710678118654752f   // cos(pi/4)
#define REPS1 32
#define REPS2 32

__device__ __forceinline__ float2 cmad2(float2 A, float2 a, float2 B, float2 b) {
  return make_float2(A.x*a.x - A.y*a.y + B.x*b.x - B.y*b.y,
                     A.x*a.y + A.y*a.x + B.x*b.y + B.y*b.x);
}

template<int CTRL>
__device__ __forceinline__ float dpps(float v) {
  int r = __builtin_amdgcn_update_dpp(__float_as_int(v), __float_as_int(v),
                                      CTRL, 0xF, 0xF, false);
  return __int_as_float(r);
}

// partner value at lane^M — R10-proven prims only
template<int M>
__device__ __forceinline__ float lxs(float v, int lane) {
  if constexpr (M == 1)       return dpps<0xB1>(v);    // quad_perm(1,0,3,2)
  else if constexpr (M == 2)  return dpps<0x4E>(v);    // quad_perm(2,3,0,1)
  else if constexpr (M == 8)  return dpps<0x128>(v);   // row_ror:8
  else {
    int addr = (lane ^ M) << 2;
    return __int_as_float(__builtin_amdgcn_ds_bpermute(addr, __float_as_int(v)));
  }
}

template<int M>
__device__ __forceinline__ void xl8(const float2 (&z)[4], int lane,
                                    float (&px)[4], float (&py)[4]) {
#pragma unroll
  for (int j = 0; j < 4; ++j) px[j] = lxs<M>(z[j].x, lane);
#pragma unroll
  for (int j = 0; j < 4; ++j) py[j] = lxs<M>(z[j].y, lane);
}

// ---- gates (coefficient-passing, batched comm — R10-proven) ----------------
template<int M>
__device__ __forceinline__ void rzdc(float2 (&z)[4], int lane, float c, float s) {
#pragma unroll
  for (int j = 0; j < 4; ++j) {
    bool hi;
    if constexpr (M < 64) hi = (lane & M) != 0;
    else                  hi = (j & (M >> 6)) != 0;
    float si = hi ? s : -s;
    z[j] = make_float2(c * z[j].x - si * z[j].y,
                       c * z[j].y + si * z[j].x);
  }
}

template<int M>
__device__ __forceinline__ void gate1r(float2 (&z)[4],
                                       float2 u00, float2 u01,
                                       float2 u10, float2 u11) {
  constexpr int jb = M >> 6;
#pragma unroll
  for (int j = 0; j < 4; ++j) {
    if ((j & jb) == 0) {
      float2 a = z[j], b = z[j + jb];
      z[j]      = cmad2(u00, a, u01, b);
      z[j + jb] = cmad2(u10, a, u11, b);
    }
  }
}

template<int M>
__device__ __forceinline__ void gate1c(float2 (&z)[4], int lane,
                                       float2 u00, float2 u01,
                                       float2 u10, float2 u11) {
  float px[4], py[4];
  xl8<M>(z, lane, px, py);
  bool hi = (lane & M) != 0;
  float2 A = hi ? u11 : u00;
  float2 B = hi ? u10 : u01;
#pragma unroll
  for (int j = 0; j < 4; ++j)
    z[j] = cmad2(A, z[j], B, make_float2(px[j], py[j]));
}

template<int M>
__device__ __forceinline__ void rygc(float2 (&z)[4], int lane, float c, float s) {
  if constexpr (M < 64) {
    float px[4], py[4];
    xl8<M>(z, lane, px, py);
    float sg = (lane & M) ? s : -s;
#pragma unroll
    for (int j = 0; j < 4; ++j)
      z[j] = make_float2(c * z[j].x + sg * px[j], c * z[j].y + sg * py[j]);
  } else {
    gate1r<M>(z, make_float2(c, 0.f), make_float2(-s, 0.f),
                 make_float2(s, 0.f), make_float2(c, 0.f));
  }
}

template<int M>
__device__ __forceinline__ void u3c(float2 (&z)[4], int lane,
                                    float2 u00, float2 u01,
                                    float2 u10, float2 u11) {
  if constexpr (M < 64) gate1c<M>(z, lane, u00, u01, u10, u11);
  else                  gate1r<M>(z, u00, u01, u10, u11);
}

template<int MC, int MT>
__device__ __forceinline__ void cnotg(float2 (&z)[4], int lane) {
  if constexpr (MT < 64) {
    float px[4], py[4];
#pragma unroll
    for (int j = 0; j < 4; ++j)
      if ((MC < 64) || (((j << 6) & MC) != 0)) px[j] = lxs<MT>(z[j].x, lane);
#pragma unroll
    for (int j = 0; j < 4; ++j)
      if ((MC < 64) || (((j << 6) & MC) != 0)) py[j] = lxs<MT>(z[j].y, lane);
#pragma unroll
    for (int j = 0; j < 4; ++j) {
      if ((MC < 64) || (((j << 6) & MC) != 0)) {
        bool sel = (MC >= 64) || ((lane & MC) != 0);
        z[j].x = sel ? px[j] : z[j].x;
        z[j].y = sel ? py[j] : z[j].y;
      }
    }
  } else {
    constexpr int jb = MT >> 6;
#pragma unroll
    for (int j = 0; j < 4; ++j) {
      if ((j & jb) == 0) {
        if (MC >= 64) {
          constexpr int cjb = MC >> 6;
          if ((j & cjb) != 0) { float2 t = z[j]; z[j] = z[j + jb]; z[j + jb] = t; }
        } else {
          bool sel = (lane & MC) != 0;
          float2 a = z[j], b = z[j + jb];
          z[j]      = make_float2(sel ? b.x : a.x, sel ? b.y : a.y);
          z[j + jb] = make_float2(sel ? a.x : b.x, sel ? a.y : b.y);
        }
      }
    }
  }
}

template<int MA, int MB, int MF>
__device__ __forceinline__ void blockgc(float2 (&z)[4], int lane,
                                        float2 zc, float2 y1, float2 y2) {
  rzdc<MA>(z, lane, QF, -QF);
  cnotg<MA, MB>(z, lane);
  rzdc<MB>(z, lane, zc.x, zc.y);
  rygc<MA>(z, lane, y1.x, y1.y);
  cnotg<MB, MA>(z, lane);
  rygc<MA>(z, lane, y2.x, y2.y);
  cnotg<MA, MB>(z, lane);
  rzdc<MF>(z, lane, QF, QF);
}

__device__ __forceinline__ float fast_tanh(float x) {
  float e = __expf(2.f * x);
  return 1.f - 2.f / (e + 1.f);
}

__device__ __forceinline__ float rlane(float v, int l) {
  return __int_as_float(__builtin_amdgcn_readlane(__float_as_int(v), l));
}

__device__ __forceinline__ void wsum4u(float& a, float& b, float& c, float& d,
                                       int lane) {
  a += lxs<1>(a, lane);  b += lxs<1>(b, lane);
  c += lxs<1>(c, lane);  d += lxs<1>(d, lane);
  a += lxs<2>(a, lane);  b += lxs<2>(b, lane);
  c += lxs<2>(c, lane);  d += lxs<2>(d, lane);
  a += lxs<4>(a, lane);  b += lxs<4>(b, lane);
  c += lxs<4>(c, lane);  d += lxs<4>(d, lane);
  a += lxs<8>(a, lane);  b += lxs<8>(b, lane);
  c += lxs<8>(c, lane);  d += lxs<8>(d, lane);
  a += lxs<16>(a, lane); b += lxs<16>(b, lane);
  c += lxs<16>(c, lane); d += lxs<16>(d, lane);
  a = rlane(a, 0) + rlane(a, 32);
  b = rlane(b, 0) + rlane(b, 32);
  c = rlane(c, 0) + rlane(c, 32);
  d = rlane(d, 0) + rlane(d, 32);
}

// ---- K1: sim, chain repeated REPS1 times (diagnostic amplification) --------
__global__ __launch_bounds__(64)
void qcnn_sim(const float* __restrict__ rz, const float* __restrict__ ry,
              const float* __restrict__ u3, float2* __restrict__ G) {
  int lane = threadIdx.x;
  int p = blockIdx.x;

  float rzl[21], ryl[14], u3l[18];
#pragma unroll
  for (int k = 0; k < 21; ++k) rzl[k] = rz[k];
#pragma unroll
  for (int k = 0; k < 14; ++k) ryl[k] = ry[k];
#pragma unroll
  for (int k = 0; k < 18; ++k) u3l[k] = u3[k];

  float2 brz[7], by1[7], by2[7];
#pragma unroll
  for (int i = 0; i < 7; ++i) {
    __sincosf(0.5f * rzl[3*i+1], &brz[i].y, &brz[i].x);
    __sincosf(0.5f * ryl[2*i],   &by1[i].y, &by1[i].x);
    __sincosf(0.5f * ryl[2*i+1], &by2[i].y, &by2[i].x);
  }
  float2 U00[6], U01[6], U10[6], U11[6];
#pragma unroll
  for (int g = 0; g < 6; ++g) {
    float s, c;   __sincosf(0.5f * u3l[3*g], &s, &c);
    float sp, cp; __sincosf(u3l[3*g+1], &sp, &cp);
    float sl, cl; __sincosf(u3l[3*g+2], &sl, &cl);
    float spl, cpl; __sincosf(u3l[3*g+1] + u3l[3*g+2], &spl, &cpl);
    U00[g] = make_float2(c, 0.f);
    U01[g] = make_float2(-cl * s, -sl * s);
    U10[g] = make_float2(cp * s, sp * s);
    U11[g] = make_float2(cpl * c, spl * c);
  }

  float2 z[4];
#pragma unroll 1
  for (int it = 0; it < REPS1; ++it) {
    // opaque zero: re-materialized every iteration -> no LICM of the chain
    float zero;
    asm volatile("v_mov_b32 %0, 0" : "=v"(zero));
#pragma unroll
    for (int j = 0; j < 4; ++j) {
      int k = (j << 6) | lane;
      z[j] = make_float2((__popc(k) == p ? 1.f : 0.f) + zero, zero);
    }

    // masks: q0=8 q1=1 q2=4 q3=64 q4=16 q5=128 q6=32 q7=2
    blockgc<1, 8, 8>(z, lane, brz[0], by1[0], by2[0]);      // block(1,0) fin=0
    blockgc<64, 4, 4>(z, lane, brz[1], by1[1], by2[1]);     // block(3,2)
    blockgc<128, 16, 16>(z, lane, brz[2], by1[2], by2[2]);  // block(5,4)
    blockgc<2, 32, 32>(z, lane, brz[3], by1[3], by2[3]);    // block(7,6)
    u3c<1>(z, lane, U00[0], U01[0], U10[0], U11[0]);        // u3 q1
    u3c<64>(z, lane, U00[1], U01[1], U10[1], U11[1]);       // u3 q3
    u3c<128>(z, lane, U00[2], U01[2], U10[2], U11[2]);      // u3 q5
    u3c<2>(z, lane, U00[3], U01[3], U10[3], U11[3]);        // u3 q7
    blockgc<64, 1, 1>(z, lane, brz[4], by1[4], by2[4]);     // block(3,1) fin=1
    blockgc<2, 128, 1>(z, lane, brz[5], by1[5], by2[5]);    // block(7,5) fin=1
    blockgc<128, 64, 64>(z, lane, brz[6], by1[6], by2[6]);  // block(5,3) fin=3
    u3c<64>(z, lane, U00[4], U01[4], U10[4], U11[4]);       // u3 q3
    u3c<2>(z, lane, U00[5], U01[5], U10[5], U11[5]);        // u3 q7

    // keep this iteration's result live (no collapse of the 32 reps)
    asm volatile("" :: "v"(z[0].x), "v"(z[0].y), "v"(z[1].x), "v"(z[1].y),
                       "v"(z[2].x), "v"(z[2].y), "v"(z[3].x), "v"(z[3].y));
  }

#pragma unroll
  for (int j = 0; j < 4; ++j)
    G[p * 256 + (j << 6) + lane] = z[j];
}

// ---- K2: stage G, reduce repeated REPS2 times, then eval -------------------
__global__ __launch_bounds__(256)
void qcnn_eval(const float* __restrict__ x, const float2* __restrict__ G,
               const float* __restrict__ W1, const float* __restrict__ b1,
               const float* __restrict__ W2, const float* __restrict__ b2,
               float* __restrict__ out, int B) {
  __shared__ float2 gl[9 * 256];
  __shared__ float4 stab[45];
  int tid = threadIdx.x;
  int wid = tid >> 6, lane = tid & 63;

  int i = blockIdx.x * 256 + tid;
  float2 tp = reinterpret_cast<const float2*>(x)[i < B ? i : 0];

  float W1l[20], b1l[10], W2l[10], b2l;
#pragma unroll
  for (int k = 0; k < 20; ++k) W1l[k] = W1[k];
#pragma unroll
  for (int k = 0; k < 10; ++k) b1l[k] = b1[k];
#pragma unroll
  for (int k = 0; k < 10; ++k) W2l[k] = W2[k];
  b2l = b2[0];

#pragma unroll
  for (int w = 0; w < 9; ++w)
    gl[w * 256 + tid] = G[w * 256 + tid];

  float th = tp.x, ph = tp.y;
  float stt, ct;
  __sincosf(0.5f * th, &stt, &ct);
  float c1, s1;
  __sincosf(ph, &s1, &c1);

  __syncthreads();

  float z7 = (lane & 2) ? -1.f : 1.f;
#pragma unroll 1
  for (int rep = 0; rep < REPS2; ++rep) {
    float zero;
    asm volatile("v_mov_b32 %0, 0" : "=v"(zero));   // opaque seed per rep
    for (int pr = wid; pr < 45; pr += 4) {
      int pp = 0, base = 0, s = pr;
      while (s >= base + 9 - pp) { base += 9 - pp; ++pp; }
      int qq = pp + (s - base);

      float Ar = zero, Ai = zero, Br = zero, Bi = zero;
#pragma unroll
      for (int m = 0; m < 4; ++m) {
        float2 a = gl[pp * 256 + (m << 6) + lane];
        float2 b = gl[qq * 256 + (m << 6) + lane];
        float cr = a.x * b.x + a.y * b.y;     // conj(a)*b
        float ci = a.x * b.y - a.y * b.x;
        if (m & 1) { Br += cr; Bi += ci; } else { Ar += cr; Ai += ci; }
      }
      float v0 = Ar - Br;                     // S3 re
      float v1 = Ai - Bi;                     // S3 im
      float v2 = z7 * (Ar + Br);              // S7 re
      float v3 = z7 * (Ai + Bi);              // S7 im
      wsum4u(v0, v1, v2, v3, lane);
      if (lane == 0) {
        float sc = (pp == qq) ? 1.f : 2.f;    // Hermitian fold
        stab[pr] = make_float4(sc * v0, sc * v1, sc * v2, sc * v3);
      }
    }
  }
  __syncthreads();

  if (i >= B) return;

  float cpw[17], spw[17];
  cpw[0] = 1.f; spw[0] = 1.f;
#pragma unroll
  for (int k = 1; k < 17; ++k) { cpw[k] = cpw[k-1] * ct; spw[k] = spw[k-1] * stt; }

  float cd[9], sd[9];
  cd[0] = 1.f; sd[0] = 0.f;
  cd[1] = c1;  sd[1] = s1;
#pragma unroll
  for (int d = 2; d < 9; ++d) {
    cd[d] = cd[d-1] * c1 - sd[d-1] * s1;
    sd[d] = sd[d-1] * c1 + cd[d-1] * s1;
  }

  float f3 = 0.f, f7 = 0.f;
  int sidx = 0;
#pragma unroll
  for (int pp = 0; pp < 9; ++pp) {
#pragma unroll
    for (int qq = pp; qq < 9; ++qq) {
      float4 s4 = stab[sidx]; ++sidx;
      float w = cpw[16 - pp - qq] * spw[pp + qq];
      int d = qq - pp;
      f3 += w * (s4.x * cd[d] - s4.y * sd[d]);
      f7 += w * (s4.z * cd[d] - s4.w * sd[d]);
    }
  }

  float acc = b2l;
#pragma unroll
  for (int j = 0; j < 10; ++j) {
    float h = fast_tanh(f3 * W1l[j] + f7 * W1l[10 + j] + b1l[j]);
    acc += h * W2l[j];
  }
  out[i] = 1.f / (1.f + __expf(-acc));
}

extern "C" void kernel_launch(void* const* d_in, const int* in_sizes, int n_in,
                              void* d_out, int out_size, void* d_ws, size_t ws_size,
                              hipStream_t stream) {
  const float* x  = (const float*)d_in[0];
  const float* rz = (const float*)d_in[1];
  const float* ry = (const float*)d_in[2];
  const float* u3 = (const float*)d_in[3];
  const float* W1 = (const float*)d_in[4];
  const float* b1 = (const float*)d_in[5];
  const float* W2 = (const float*)d_in[6];
  const float* b2 = (const float*)d_in[7];

  float2* G = (float2*)d_ws;               // 9*256*8 = 18432 B

  qcnn_sim<<<9, 64, 0, stream>>>(rz, ry, u3, G);

  int B = in_sizes[0] / 2;                 // 65536
  qcnn_eval<<<(B + 255) / 256, 256, 0, stream>>>(x, G, W1, b1, W2, b2,
                                                 (float*)d_out, B);
}

// Round 12
// 16.525 us; speedup vs baseline: 17.3586x; 17.3586x over previous
//
#include <hip/hip_runtime.h>
#include <math.h>

// ---------------------------------------------------------------------------
// QCNN forward — 2 dispatches. R11: gather-style reduce (zero cross-lane).
//
// feat_w = sum_{p<=q} S_w[p,q] c^{16-p-q} s^{p+q} (Re S cos(d phi) - Im S sin(d phi))
// S_w[p,q] = sum_k z_k conj(G[k,p]) G[k,q],  G[:,p] = U*(indicator popc = p)
//
// R11 diagnostic found: T_sim ~2.4us, per-block reduce ~6.4us (cross-lane
// butterfly chains), harness floor ~8.7us. This round: reduce restructured as
// lane=pair / wave=k-chunk serial gather from padded LDS (stride 257 ->
// 9 rows on 9 distinct banks, same-row broadcast). No wsum butterflies.
//
// Qubit->mask: q0=8 q1=1 q2=4 q3=64 q4=16 q5=128 q6=32 q7=2
// Z-signs: q3 -> k bit6 (= wave&1 for 64-k chunks); q7 -> k bit1.
// ---------------------------------------------------------------------------

#define QF 0.70710678118654752f   // cos(pi/4)
#define GSTR 257                  // padded float2 stride of G rows in LDS

__device__ __forceinline__ float2 cmad2(float2 A, float2 a, float2 B, float2 b) {
  return make_float2(A.x*a.x - A.y*a.y + B.x*b.x - B.y*b.y,
                     A.x*a.y + A.y*a.x + B.x*b.y + B.y*b.x);
}

template<int CTRL>
__device__ __forceinline__ float dpps(float v) {
  int r = __builtin_amdgcn_update_dpp(__float_as_int(v), __float_as_int(v),
                                      CTRL, 0xF, 0xF, false);
  return __int_as_float(r);
}

// partner value at lane^M — R10-proven prims only
template<int M>
__device__ __forceinline__ float lxs(float v, int lane) {
  if constexpr (M == 1)       return dpps<0xB1>(v);    // quad_perm(1,0,3,2)
  else if constexpr (M == 2)  return dpps<0x4E>(v);    // quad_perm(2,3,0,1)
  else if constexpr (M == 8)  return dpps<0x128>(v);   // row_ror:8
  else {
    int addr = (lane ^ M) << 2;
    return __int_as_float(__builtin_amdgcn_ds_bpermute(addr, __float_as_int(v)));
  }
}

template<int M>
__device__ __forceinline__ void xl8(const float2 (&z)[4], int lane,
                                    float (&px)[4], float (&py)[4]) {
#pragma unroll
  for (int j = 0; j < 4; ++j) px[j] = lxs<M>(z[j].x, lane);
#pragma unroll
  for (int j = 0; j < 4; ++j) py[j] = lxs<M>(z[j].y, lane);
}

// ---- gates (coefficient-passing, batched comm — R10-proven) ----------------
template<int M>
__device__ __forceinline__ void rzdc(float2 (&z)[4], int lane, float c, float s) {
#pragma unroll
  for (int j = 0; j < 4; ++j) {
    bool hi;
    if constexpr (M < 64) hi = (lane & M) != 0;
    else                  hi = (j & (M >> 6)) != 0;
    float si = hi ? s : -s;
    z[j] = make_float2(c * z[j].x - si * z[j].y,
                       c * z[j].y + si * z[j].x);
  }
}

template<int M>
__device__ __forceinline__ void gate1r(float2 (&z)[4],
                                       float2 u00, float2 u01,
                                       float2 u10, float2 u11) {
  constexpr int jb = M >> 6;
#pragma unroll
  for (int j = 0; j < 4; ++j) {
    if ((j & jb) == 0) {
      float2 a = z[j], b = z[j + jb];
      z[j]      = cmad2(u00, a, u01, b);
      z[j + jb] = cmad2(u10, a, u11, b);
    }
  }
}

template<int M>
__device__ __forceinline__ void gate1c(float2 (&z)[4], int lane,
                                       float2 u00, float2 u01,
                                       float2 u10, float2 u11) {
  float px[4], py[4];
  xl8<M>(z, lane, px, py);
  bool hi = (lane & M) != 0;
  float2 A = hi ? u11 : u00;
  float2 B = hi ? u10 : u01;
#pragma unroll
  for (int j = 0; j < 4; ++j)
    z[j] = cmad2(A, z[j], B, make_float2(px[j], py[j]));
}

template<int M>
__device__ __forceinline__ void rygc(float2 (&z)[4], int lane, float c, float s) {
  if constexpr (M < 64) {
    float px[4], py[4];
    xl8<M>(z, lane, px, py);
    float sg = (lane & M) ? s : -s;
#pragma unroll
    for (int j = 0; j < 4; ++j)
      z[j] = make_float2(c * z[j].x + sg * px[j], c * z[j].y + sg * py[j]);
  } else {
    gate1r<M>(z, make_float2(c, 0.f), make_float2(-s, 0.f),
                 make_float2(s, 0.f), make_float2(c, 0.f));
  }
}

template<int M>
__device__ __forceinline__ void u3c(float2 (&z)[4], int lane,
                                    float2 u00, float2 u01,
                                    float2 u10, float2 u11) {
  if constexpr (M < 64) gate1c<M>(z, lane, u00, u01, u10, u11);
  else                  gate1r<M>(z, u00, u01, u10, u11);
}

template<int MC, int MT>
__device__ __forceinline__ void cnotg(float2 (&z)[4], int lane) {
  if constexpr (MT < 64) {
    float px[4], py[4];
#pragma unroll
    for (int j = 0; j < 4; ++j)
      if ((MC < 64) || (((j << 6) & MC) != 0)) px[j] = lxs<MT>(z[j].x, lane);
#pragma unroll
    for (int j = 0; j < 4; ++j)
      if ((MC < 64) || (((j << 6) & MC) != 0)) py[j] = lxs<MT>(z[j].y, lane);
#pragma unroll
    for (int j = 0; j < 4; ++j) {
      if ((MC < 64) || (((j << 6) & MC) != 0)) {
        bool sel = (MC >= 64) || ((lane & MC) != 0);
        z[j].x = sel ? px[j] : z[j].x;
        z[j].y = sel ? py[j] : z[j].y;
      }
    }
  } else {
    constexpr int jb = MT >> 6;
#pragma unroll
    for (int j = 0; j < 4; ++j) {
      if ((j & jb) == 0) {
        if (MC >= 64) {
          constexpr int cjb = MC >> 6;
          if ((j & cjb) != 0) { float2 t = z[j]; z[j] = z[j + jb]; z[j + jb] = t; }
        } else {
          bool sel = (lane & MC) != 0;
          float2 a = z[j], b = z[j + jb];
          z[j]      = make_float2(sel ? b.x : a.x, sel ? b.y : a.y);
          z[j + jb] = make_float2(sel ? a.x : b.x, sel ? a.y : b.y);
        }
      }
    }
  }
}

template<int MA, int MB, int MF>
__device__ __forceinline__ void blockgc(float2 (&z)[4], int lane,
                                        float2 zc, float2 y1, float2 y2) {
  rzdc<MA>(z, lane, QF, -QF);
  cnotg<MA, MB>(z, lane);
  rzdc<MB>(z, lane, zc.x, zc.y);
  rygc<MA>(z, lane, y1.x, y1.y);
  cnotg<MB, MA>(z, lane);
  rygc<MA>(z, lane, y2.x, y2.y);
  cnotg<MA, MB>(z, lane);
  rzdc<MF>(z, lane, QF, QF);
}

__device__ __forceinline__ float fast_tanh(float x) {
  float e = __expf(2.f * x);
  return 1.f - 2.f / (e + 1.f);
}

// ---- K1: simulate one indicator state per block (1 wave), write G ----------
__global__ __launch_bounds__(64)
void qcnn_sim(const float* __restrict__ rz, const float* __restrict__ ry,
              const float* __restrict__ u3, float2* __restrict__ G) {
  int lane = threadIdx.x;
  int p = blockIdx.x;

  float rzl[21], ryl[14], u3l[18];
#pragma unroll
  for (int k = 0; k < 21; ++k) rzl[k] = rz[k];
#pragma unroll
  for (int k = 0; k < 14; ++k) ryl[k] = ry[k];
#pragma unroll
  for (int k = 0; k < 18; ++k) u3l[k] = u3[k];

  float2 brz[7], by1[7], by2[7];
#pragma unroll
  for (int i = 0; i < 7; ++i) {
    __sincosf(0.5f * rzl[3*i+1], &brz[i].y, &brz[i].x);
    __sincosf(0.5f * ryl[2*i],   &by1[i].y, &by1[i].x);
    __sincosf(0.5f * ryl[2*i+1], &by2[i].y, &by2[i].x);
  }
  float2 U00[6], U01[6], U10[6], U11[6];
#pragma unroll
  for (int g = 0; g < 6; ++g) {
    float s, c;   __sincosf(0.5f * u3l[3*g], &s, &c);
    float sp, cp; __sincosf(u3l[3*g+1], &sp, &cp);
    float sl, cl; __sincosf(u3l[3*g+2], &sl, &cl);
    float spl, cpl; __sincosf(u3l[3*g+1] + u3l[3*g+2], &spl, &cpl);
    U00[g] = make_float2(c, 0.f);
    U01[g] = make_float2(-cl * s, -sl * s);
    U10[g] = make_float2(cp * s, sp * s);
    U11[g] = make_float2(cpl * c, spl * c);
  }

  float2 z[4];
#pragma unroll
  for (int j = 0; j < 4; ++j) {
    int k = (j << 6) | lane;
    z[j] = make_float2(__popc(k) == p ? 1.f : 0.f, 0.f);
  }

  // masks: q0=8 q1=1 q2=4 q3=64 q4=16 q5=128 q6=32 q7=2
  blockgc<1, 8, 8>(z, lane, brz[0], by1[0], by2[0]);      // block(1,0) fin=0
  blockgc<64, 4, 4>(z, lane, brz[1], by1[1], by2[1]);     // block(3,2)
  blockgc<128, 16, 16>(z, lane, brz[2], by1[2], by2[2]);  // block(5,4)
  blockgc<2, 32, 32>(z, lane, brz[3], by1[3], by2[3]);    // block(7,6)
  u3c<1>(z, lane, U00[0], U01[0], U10[0], U11[0]);        // u3 q1
  u3c<64>(z, lane, U00[1], U01[1], U10[1], U11[1]);       // u3 q3
  u3c<128>(z, lane, U00[2], U01[2], U10[2], U11[2]);      // u3 q5
  u3c<2>(z, lane, U00[3], U01[3], U10[3], U11[3]);        // u3 q7
  blockgc<64, 1, 1>(z, lane, brz[4], by1[4], by2[4]);     // block(3,1) fin=1
  blockgc<2, 128, 1>(z, lane, brz[5], by1[5], by2[5]);    // block(7,5) fin=1
  blockgc<128, 64, 64>(z, lane, brz[6], by1[6], by2[6]);  // block(5,3) fin=3
  u3c<64>(z, lane, U00[4], U01[4], U10[4], U11[4]);       // u3 q3
  u3c<2>(z, lane, U00[5], U01[5], U10[5], U11[5]);        // u3 q7

#pragma unroll
  for (int j = 0; j < 4; ++j)
    G[p * 256 + (j << 6) + lane] = z[j];
}

// triangular decode: idx in [0,45) -> (pp, qq), pp<=qq
__device__ __forceinline__ void tdec(int idx, int& pp, int& qq) {
  int base = 0; pp = 0;
  while (idx >= base + 9 - pp) { base += 9 - pp; ++pp; }
  qq = pp + (idx - base);
}

// ---- K2: stage G (padded), gather-reduce (no cross-lane), eval -------------
__global__ __launch_bounds__(256)
void qcnn_eval(const float* __restrict__ x, const float2* __restrict__ G,
               const float* __restrict__ W1, const float* __restrict__ b1,
               const float* __restrict__ W2, const float* __restrict__ b2,
               float* __restrict__ out, int B) {
  __shared__ float2 gl[9 * GSTR];      // padded rows: bank(pp row) distinct
  __shared__ float4 part[4][45];
  __shared__ float4 stab[45];
  int tid = threadIdx.x;
  int wid = tid >> 6, lane = tid & 63;

  int i = blockIdx.x * 256 + tid;
  float2 tp = reinterpret_cast<const float2*>(x)[i < B ? i : 0];

  float W1l[20], b1l[10], W2l[10], b2l;
#pragma unroll
  for (int k = 0; k < 20; ++k) W1l[k] = W1[k];
#pragma unroll
  for (int k = 0; k < 10; ++k) b1l[k] = b1[k];
#pragma unroll
  for (int k = 0; k < 10; ++k) W2l[k] = W2[k];
  b2l = b2[0];

#pragma unroll
  for (int w = 0; w < 9; ++w)
    gl[w * GSTR + tid] = G[w * 256 + tid];

  float th = tp.x, ph = tp.y;
  float stt, ct;
  __sincosf(0.5f * th, &stt, &ct);
  float c1, s1;
  __sincosf(ph, &s1, &c1);

  __syncthreads();

  // ---- reduce: lane = pair (45 of 64), wave = 64-k chunk. No cross-lane.
  // z3 sign over this wave's chunk = (wid&1) ? -1 : +1 (k bit6).
  // z7 sign = k bit1 -> static per unrolled slot (kk&2).
  if (lane < 45) {
    int pp, qq; tdec(lane, pp, qq);
    const float2* rp = &gl[pp * GSTR + (wid << 6)];
    const float2* rq = &gl[qq * GSTR + (wid << 6)];
    float pr_ = 0.f, pi_ = 0.f, mr_ = 0.f, mi_ = 0.f;  // z7=+ / z7=- groups
#pragma unroll
    for (int kk = 0; kk < 64; kk += 4) {
#pragma unroll
      for (int u = 0; u < 4; ++u) {
        float2 a = rp[kk + u];
        float2 b = rq[kk + u];
        float cr = a.x * b.x + a.y * b.y;    // conj(a)*b
        float ci = a.x * b.y - a.y * b.x;
        if (u < 2) { pr_ += cr; pi_ += ci; }  // k bit1 = 0 -> z7 = +1
        else       { mr_ += cr; mi_ += ci; }  // k bit1 = 1 -> z7 = -1
      }
    }
    float s3w = (wid & 1) ? -1.f : 1.f;
    // S3 partial = s3w * (sum); S7 partial = (plus - minus)
    part[wid][lane] = make_float4(s3w * (pr_ + mr_), s3w * (pi_ + mi_),
                                  pr_ - mr_, pi_ - mi_);
  }
  __syncthreads();

  if (tid < 45) {
    int pp, qq; tdec(tid, pp, qq);
    float4 p0 = part[0][tid], p1 = part[1][tid];
    float4 p2 = part[2][tid], p3 = part[3][tid];
    float sc = (pp == qq) ? 1.f : 2.f;       // Hermitian fold
    stab[tid] = make_float4(sc * (p0.x + p1.x + p2.x + p3.x),
                            sc * (p0.y + p1.y + p2.y + p3.y),
                            sc * (p0.z + p1.z + p2.z + p3.z),
                            sc * (p0.w + p1.w + p2.w + p3.w));
  }
  __syncthreads();

  if (i >= B) return;

  float cpw[17], spw[17];
  cpw[0] = 1.f; spw[0] = 1.f;
#pragma unroll
  for (int k = 1; k < 17; ++k) { cpw[k] = cpw[k-1] * ct; spw[k] = spw[k-1] * stt; }

  float cd[9], sd[9];
  cd[0] = 1.f; sd[0] = 0.f;
  cd[1] = c1;  sd[1] = s1;
#pragma unroll
  for (int d = 2; d < 9; ++d) {
    cd[d] = cd[d-1] * c1 - sd[d-1] * s1;
    sd[d] = sd[d-1] * c1 + cd[d-1] * s1;
  }

  float f3 = 0.f, f7 = 0.f;
  int sidx = 0;
#pragma unroll
  for (int pp = 0; pp < 9; ++pp) {
#pragma unroll
    for (int qq = pp; qq < 9; ++qq) {
      float4 s4 = stab[sidx]; ++sidx;
      float w = cpw[16 - pp - qq] * spw[pp + qq];
      int d = qq - pp;
      f3 += w * (s4.x * cd[d] - s4.y * sd[d]);
      f7 += w * (s4.z * cd[d] - s4.w * sd[d]);
    }
  }

  float acc = b2l;
#pragma unroll
  for (int j = 0; j < 10; ++j) {
    float h = fast_tanh(f3 * W1l[j] + f7 * W1l[10 + j] + b1l[j]);
    acc += h * W2l[j];
  }
  out[i] = 1.f / (1.f + __expf(-acc));
}

extern "C" void kernel_launch(void* const* d_in, const int* in_sizes, int n_in,
                              void* d_out, int out_size, void* d_ws, size_t ws_size,
                              hipStream_t stream) {
  const float* x  = (const float*)d_in[0];
  const float* rz = (const float*)d_in[1];
  const float* ry = (const float*)d_in[2];
  const float* u3 = (const float*)d_in[3];
  const float* W1 = (const float*)d_in[4];
  const float* b1 = (const float*)d_in[5];
  const float* W2 = (const float*)d_in[6];
  const float* b2 = (const float*)d_in[7];

  float2* G = (float2*)d_ws;               // 9*256*8 = 18432 B

  qcnn_sim<<<9, 64, 0, stream>>>(rz, ry, u3, G);

  int B = in_sizes[0] / 2;                 // 65536
  qcnn_eval<<<(B + 255) / 256, 256, 0, stream>>>(x, G, W1, b1, W2, b2,
                                                 (float*)d_out, B);
}